// Round 1
// baseline (885.042 us; speedup 1.0000x reference)
//
#include <hip/hip_runtime.h>
#include <hip/hip_bf16.h>

// BinaryLinear: y = x @ sign(W)^T + sign(b)
//   x: [8192, 4096] f32, W: [4096, 4096] f32 (row-major, K-major), b: [4096] f32
//   out: [8192, 4096] f32
// Strategy: cast x -> bf16 (RNE) and W -> sign as bf16 (+1/-1) during LDS
// staging; bf16 MFMA 16x16x32 with fp32 accumulation. 128x128 block tile,
// 4 waves x (4x4 MFMA tiles of 16x16). K-step 32.

typedef __attribute__((ext_vector_type(8))) short short8;   // 8 bf16 = 4 VGPRs
typedef __attribute__((ext_vector_type(4))) float f32x4;    // MFMA acc

constexpr int M = 8192;
constexpr int N = 4096;
constexpr int K = 4096;

constexpr int MT = 128;   // block tile M
constexpr int NT = 128;   // block tile N
constexpr int KT = 32;    // K step
constexpr int LDSS = 40;  // LDS row stride in bf16 elems: 32 + 8 pad (keeps 16B align)

// f32 -> bf16 bits, round-to-nearest-even (inputs are finite normals; no NaN path)
__device__ __forceinline__ unsigned short f2b(float f) {
    unsigned int u = __builtin_bit_cast(unsigned int, f);
    u += 0x7FFFu + ((u >> 16) & 1u);
    return (unsigned short)(u >> 16);
}

__global__ __launch_bounds__(256) void binlin_kernel(
    const float* __restrict__ X, const float* __restrict__ W,
    const float* __restrict__ B, float* __restrict__ OUT) {
    __shared__ unsigned short As[MT][LDSS];
    __shared__ unsigned short Bs[NT][LDSS];

    const int tid  = threadIdx.x;
    const int lane = tid & 63;
    const int wave = tid >> 6;        // 0..3
    const int wm   = wave >> 1;       // 0..1  (wave's 64-row half)
    const int wn   = wave & 1;        // 0..1  (wave's 64-col half)

    const int m0 = blockIdx.y * MT;
    const int n0 = blockIdx.x * NT;

    const int rl = lane & 15;         // row-in-tile for A frag / col for B frag
    const int kq = (lane >> 4) * 8;   // k quad offset

    f32x4 acc[4][4];
#pragma unroll
    for (int mi = 0; mi < 4; ++mi)
#pragma unroll
        for (int ni = 0; ni < 4; ++ni)
            acc[mi][ni] = (f32x4){0.f, 0.f, 0.f, 0.f};

    for (int k0 = 0; k0 < K; k0 += KT) {
        // ---- stage A tile: 128 rows x 32 k of x, f32 -> bf16 ----
        // 1024 float4-groups; 256 threads x 4 iterations
#pragma unroll
        for (int it = 0; it < 4; ++it) {
            int g   = tid + it * 256;       // 0..1023
            int row = g >> 3;               // 0..127
            int c4  = (g & 7) << 2;         // 0,4,..,28
            float4 v = *reinterpret_cast<const float4*>(
                &X[(size_t)(m0 + row) * K + k0 + c4]);
            ushort4 h;
            h.x = f2b(v.x); h.y = f2b(v.y); h.z = f2b(v.z); h.w = f2b(v.w);
            *reinterpret_cast<ushort4*>(&As[row][c4]) = h;
        }
        // ---- stage B tile: 128 rows x 32 k of W, f32 -> sign bf16 ----
#pragma unroll
        for (int it = 0; it < 4; ++it) {
            int g   = tid + it * 256;
            int row = g >> 3;
            int c4  = (g & 7) << 2;
            float4 v = *reinterpret_cast<const float4*>(
                &W[(size_t)(n0 + row) * K + k0 + c4]);
            ushort4 h;
            h.x = (v.x >= 0.f) ? 0x3F80u : 0xBF80u;
            h.y = (v.y >= 0.f) ? 0x3F80u : 0xBF80u;
            h.z = (v.z >= 0.f) ? 0x3F80u : 0xBF80u;
            h.w = (v.w >= 0.f) ? 0x3F80u : 0xBF80u;
            *reinterpret_cast<ushort4*>(&Bs[row][c4]) = h;
        }
        __syncthreads();

        // ---- compute: 16 MFMA per wave ----
        short8 a[4], b[4];
#pragma unroll
        for (int mi = 0; mi < 4; ++mi)
            a[mi] = *reinterpret_cast<const short8*>(&As[wm * 64 + mi * 16 + rl][kq]);
#pragma unroll
        for (int ni = 0; ni < 4; ++ni)
            b[ni] = *reinterpret_cast<const short8*>(&Bs[wn * 64 + ni * 16 + rl][kq]);
#pragma unroll
        for (int mi = 0; mi < 4; ++mi)
#pragma unroll
            for (int ni = 0; ni < 4; ++ni)
                acc[mi][ni] = __builtin_amdgcn_mfma_f32_16x16x32_bf16(
                    a[mi], b[ni], acc[mi][ni], 0, 0, 0);
        __syncthreads();
    }

    // ---- epilogue: C/D layout col=lane&15, row=(lane>>4)*4+reg; add sign(bias) ----
#pragma unroll
    for (int ni = 0; ni < 4; ++ni) {
        int gcol = n0 + wn * 64 + ni * 16 + rl;
        float sb = (B[gcol] >= 0.f) ? 1.f : -1.f;
#pragma unroll
        for (int mi = 0; mi < 4; ++mi) {
            int growb = m0 + wm * 64 + mi * 16 + (lane >> 4) * 4;
#pragma unroll
            for (int r = 0; r < 4; ++r) {
                OUT[(size_t)(growb + r) * N + gcol] = acc[mi][ni][r] + sb;
            }
        }
    }
}

extern "C" void kernel_launch(void* const* d_in, const int* in_sizes, int n_in,
                              void* d_out, int out_size, void* d_ws, size_t ws_size,
                              hipStream_t stream) {
    const float* x  = (const float*)d_in[0];
    const float* w  = (const float*)d_in[1];
    const float* b  = (const float*)d_in[2];
    float* out      = (float*)d_out;

    dim3 grid(N / NT, M / MT);  // (32, 64)
    binlin_kernel<<<grid, dim3(256), 0, stream>>>(x, w, b, out);
}

// Round 2
// 562.944 us; speedup vs baseline: 1.5722x; 1.5722x over previous
//
#include <hip/hip_runtime.h>
#include <hip/hip_bf16.h>

// BinaryLinear: y = x @ sign(W)^T + sign(b)
//   x: [8192,4096] f32, W: [4096,4096] f32 (K-major), b: [4096] f32 -> out [8192,4096] f32
// R2: prep kernel converts X -> bf16 and W -> sign-bf16 into d_ws; GEMM uses the
// m97 structure (global_load_lds width=16 into unpadded 128x32 LDS tiles,
// 16x16x32 bf16 MFMA, 128x128 block tile, 4 waves x 4x4 tiles).

typedef __attribute__((ext_vector_type(8))) short short8;   // 8 bf16 = 4 VGPRs
typedef __attribute__((ext_vector_type(4))) float f32x4;    // MFMA acc

constexpr int M = 8192;
constexpr int N = 4096;
constexpr int K = 4096;

constexpr int MT = 128;
constexpr int NT = 128;
constexpr int KT = 32;

// f32 -> bf16 bits, round-to-nearest-even (finite inputs)
__device__ __forceinline__ unsigned short f2b(float f) {
    unsigned int u = __builtin_bit_cast(unsigned int, f);
    u += 0x7FFFu + ((u >> 16) & 1u);
    return (unsigned short)(u >> 16);
}

__device__ __forceinline__ unsigned int pack2(unsigned short lo, unsigned short hi) {
    return (unsigned int)lo | ((unsigned int)hi << 16);
}

// async global -> LDS, 16 B per lane; LDS dest is wave-uniform base + lane*16
__device__ __forceinline__ void load_lds16(const unsigned short* g, unsigned short* l) {
    __builtin_amdgcn_global_load_lds(
        (const __attribute__((address_space(1))) unsigned int*)g,
        (__attribute__((address_space(3))) unsigned int*)l, 16, 0, 0);
}

// ---------------- prep: X -> bf16, W -> sign bf16 ----------------
// one thread = 8 elements (two float4 loads, one 16B store)
__global__ __launch_bounds__(256) void prep_kernel(
    const float* __restrict__ X, const float* __restrict__ W,
    unsigned short* __restrict__ Abf, unsigned short* __restrict__ Bbf) {
    const long long NX8 = (long long)M * K / 8;  // 4,194,304
    long long i = (long long)blockIdx.x * 256 + threadIdx.x;
    if (i < NX8) {
        const float4* src = reinterpret_cast<const float4*>(X) + i * 2;
        float4 v0 = src[0], v1 = src[1];
        uint4 o;
        o.x = pack2(f2b(v0.x), f2b(v0.y));
        o.y = pack2(f2b(v0.z), f2b(v0.w));
        o.z = pack2(f2b(v1.x), f2b(v1.y));
        o.w = pack2(f2b(v1.z), f2b(v1.w));
        *reinterpret_cast<uint4*>(Abf + i * 8) = o;
    } else {
        long long j = i - NX8;  // < N*K/8 by grid construction
        const float4* src = reinterpret_cast<const float4*>(W) + j * 2;
        float4 v0 = src[0], v1 = src[1];
        auto sg = [](float f) -> unsigned short { return (f >= 0.f) ? 0x3F80u : 0xBF80u; };
        uint4 o;
        o.x = pack2(sg(v0.x), sg(v0.y));
        o.y = pack2(sg(v0.z), sg(v0.w));
        o.z = pack2(sg(v1.x), sg(v1.y));
        o.w = pack2(sg(v1.z), sg(v1.w));
        *reinterpret_cast<uint4*>(Bbf + j * 8) = o;
    }
}

// ---------------- GEMM (m97 structure) ----------------
__global__ __launch_bounds__(256) void gemm_kernel(
    const unsigned short* __restrict__ Abf, const unsigned short* __restrict__ Bbf,
    const float* __restrict__ Bias, float* __restrict__ OUT) {
    __shared__ unsigned short As[MT * KT];  // 128 rows x 32 bf16, unpadded (8 KB)
    __shared__ unsigned short Bs[NT * KT];

    const int tid  = threadIdx.x;
    const int lane = tid & 63;
    const int wave = tid >> 6;   // 0..3
    const int wm   = wave >> 1;
    const int wn   = wave & 1;

    const int m0 = blockIdx.y * MT;
    const int n0 = blockIdx.x * NT;

    const int rl = lane & 15;
    const int kq = (lane >> 4) * 8;

    // staging: wave w covers rows [w*32, w*32+32); lane L -> row +L/4, col (L&3)*8
    const int srow = wave * 32 + (lane >> 2);
    const int scol = (lane & 3) * 8;
    const unsigned short* gA = Abf + (size_t)(m0 + srow) * K + scol;
    const unsigned short* gB = Bbf + (size_t)(n0 + srow) * K + scol;
    unsigned short* lA0 = &As[(wave * 32) * KT];       // wave-uniform LDS bases
    unsigned short* lA1 = &As[(wave * 32 + 16) * KT];
    unsigned short* lB0 = &Bs[(wave * 32) * KT];
    unsigned short* lB1 = &Bs[(wave * 32 + 16) * KT];

    f32x4 acc[4][4];
#pragma unroll
    for (int mi = 0; mi < 4; ++mi)
#pragma unroll
        for (int ni = 0; ni < 4; ++ni)
            acc[mi][ni] = (f32x4){0.f, 0.f, 0.f, 0.f};

    for (int k0 = 0; k0 < K; k0 += KT) {
        load_lds16(gA + k0, lA0);
        load_lds16(gA + k0 + 16 * K, lA1);
        load_lds16(gB + k0, lB0);
        load_lds16(gB + k0 + 16 * K, lB1);
        __syncthreads();  // compiler drains vmcnt before s_barrier

        short8 a[4], b[4];
#pragma unroll
        for (int mi = 0; mi < 4; ++mi)
            a[mi] = *reinterpret_cast<const short8*>(&As[(wm * 64 + mi * 16 + rl) * KT + kq]);
#pragma unroll
        for (int ni = 0; ni < 4; ++ni)
            b[ni] = *reinterpret_cast<const short8*>(&Bs[(wn * 64 + ni * 16 + rl) * KT + kq]);
#pragma unroll
        for (int mi = 0; mi < 4; ++mi)
#pragma unroll
            for (int ni = 0; ni < 4; ++ni)
                acc[mi][ni] = __builtin_amdgcn_mfma_f32_16x16x32_bf16(
                    a[mi], b[ni], acc[mi][ni], 0, 0, 0);
        __syncthreads();
    }

    // epilogue: C/D layout col=lane&15, row=(lane>>4)*4+reg; add sign(bias)
#pragma unroll
    for (int ni = 0; ni < 4; ++ni) {
        int gcol = n0 + wn * 64 + ni * 16 + rl;
        float sb = (Bias[gcol] >= 0.f) ? 1.f : -1.f;
#pragma unroll
        for (int mi = 0; mi < 4; ++mi) {
            int growb = m0 + wm * 64 + mi * 16 + (lane >> 4) * 4;
#pragma unroll
            for (int r = 0; r < 4; ++r) {
                OUT[(size_t)(growb + r) * N + gcol] = acc[mi][ni][r] + sb;
            }
        }
    }
}

// ---------------- fallback (R1 kernel): used only if ws_size is too small ----
constexpr int LDSS = 40;
__global__ __launch_bounds__(256) void binlin_fallback(
    const float* __restrict__ X, const float* __restrict__ W,
    const float* __restrict__ B, float* __restrict__ OUT) {
    __shared__ unsigned short As[MT][LDSS];
    __shared__ unsigned short Bs[NT][LDSS];
    const int tid  = threadIdx.x;
    const int lane = tid & 63;
    const int wave = tid >> 6;
    const int wm   = wave >> 1;
    const int wn   = wave & 1;
    const int m0 = blockIdx.y * MT;
    const int n0 = blockIdx.x * NT;
    const int rl = lane & 15;
    const int kq = (lane >> 4) * 8;
    f32x4 acc[4][4];
#pragma unroll
    for (int mi = 0; mi < 4; ++mi)
#pragma unroll
        for (int ni = 0; ni < 4; ++ni)
            acc[mi][ni] = (f32x4){0.f, 0.f, 0.f, 0.f};
    for (int k0 = 0; k0 < K; k0 += KT) {
#pragma unroll
        for (int it = 0; it < 4; ++it) {
            int g = tid + it * 256, row = g >> 3, c4 = (g & 7) << 2;
            float4 v = *reinterpret_cast<const float4*>(&X[(size_t)(m0 + row) * K + k0 + c4]);
            ushort4 h;
            h.x = f2b(v.x); h.y = f2b(v.y); h.z = f2b(v.z); h.w = f2b(v.w);
            *reinterpret_cast<ushort4*>(&As[row][c4]) = h;
        }
#pragma unroll
        for (int it = 0; it < 4; ++it) {
            int g = tid + it * 256, row = g >> 3, c4 = (g & 7) << 2;
            float4 v = *reinterpret_cast<const float4*>(&W[(size_t)(n0 + row) * K + k0 + c4]);
            ushort4 h;
            h.x = (v.x >= 0.f) ? 0x3F80u : 0xBF80u;
            h.y = (v.y >= 0.f) ? 0x3F80u : 0xBF80u;
            h.z = (v.z >= 0.f) ? 0x3F80u : 0xBF80u;
            h.w = (v.w >= 0.f) ? 0x3F80u : 0xBF80u;
            *reinterpret_cast<ushort4*>(&Bs[row][c4]) = h;
        }
        __syncthreads();
        short8 a[4], b[4];
#pragma unroll
        for (int mi = 0; mi < 4; ++mi)
            a[mi] = *reinterpret_cast<const short8*>(&As[wm * 64 + mi * 16 + rl][kq]);
#pragma unroll
        for (int ni = 0; ni < 4; ++ni)
            b[ni] = *reinterpret_cast<const short8*>(&Bs[wn * 64 + ni * 16 + rl][kq]);
#pragma unroll
        for (int mi = 0; mi < 4; ++mi)
#pragma unroll
            for (int ni = 0; ni < 4; ++ni)
                acc[mi][ni] = __builtin_amdgcn_mfma_f32_16x16x32_bf16(
                    a[mi], b[ni], acc[mi][ni], 0, 0, 0);
        __syncthreads();
    }
#pragma unroll
    for (int ni = 0; ni < 4; ++ni) {
        int gcol = n0 + wn * 64 + ni * 16 + rl;
        float sb = (B[gcol] >= 0.f) ? 1.f : -1.f;
#pragma unroll
        for (int mi = 0; mi < 4; ++mi) {
            int growb = m0 + wm * 64 + mi * 16 + (lane >> 4) * 4;
#pragma unroll
            for (int r = 0; r < 4; ++r)
                OUT[(size_t)(growb + r) * N + gcol] = acc[mi][ni][r] + sb;
        }
    }
}

extern "C" void kernel_launch(void* const* d_in, const int* in_sizes, int n_in,
                              void* d_out, int out_size, void* d_ws, size_t ws_size,
                              hipStream_t stream) {
    const float* x  = (const float*)d_in[0];
    const float* w  = (const float*)d_in[1];
    const float* b  = (const float*)d_in[2];
    float* out      = (float*)d_out;

    const size_t need = ((size_t)M * K + (size_t)N * K) * sizeof(unsigned short);  // 96 MiB
    if (ws_size >= need) {
        unsigned short* Abf = (unsigned short*)d_ws;
        unsigned short* Bbf = Abf + (size_t)M * K;
        const long long total8 = (long long)(M * (long long)K + N * (long long)K) / 8;
        prep_kernel<<<dim3((unsigned)(total8 / 256)), dim3(256), 0, stream>>>(x, w, Abf, Bbf);
        dim3 grid(N / NT, M / MT);  // (32, 64)
        gemm_kernel<<<grid, dim3(256), 0, stream>>>(Abf, Bbf, b, out);
    } else {
        dim3 grid(N / NT, M / MT);
        binlin_fallback<<<grid, dim3(256), 0, stream>>>(x, w, b, out);
    }
}

// Round 3
// 434.350 us; speedup vs baseline: 2.0376x; 1.2961x over previous
//
#include <hip/hip_runtime.h>

// BinaryLinear: y = x @ sign(W)^T + sign(b)
// R3: int8 path. prep_x quantizes each row of x to i8 with per-row scale
// (s_t = rowmax/127); prep_w converts W to sign i8 (+1/-1). GEMM uses the m97
// structure with mfma_i32_16x16x64_i8 (K=64/step, same 64B LDS row geometry,
// half the K-iterations of the bf16 version). i32 accumulation is exact;
// epilogue applies s_t and sign(bias).

typedef __attribute__((ext_vector_type(4))) int   i32x4;  // i8 MFMA A/B frag (16 i8) and C/D
typedef __attribute__((ext_vector_type(8))) short short8; // bf16 frag (fallback)
typedef __attribute__((ext_vector_type(4))) float f32x4;

constexpr int M = 8192;
constexpr int N = 4096;
constexpr int K = 4096;

constexpr int MT = 128;
constexpr int NT = 128;
constexpr int KT = 64;   // i8 K-step (64 bytes per LDS row, same geometry as m97 bf16)

// async global -> LDS, 16 B per lane; LDS dest is wave-uniform base + lane*16
__device__ __forceinline__ void load_lds16(const void* g, void* l) {
    __builtin_amdgcn_global_load_lds(
        (const __attribute__((address_space(1))) unsigned int*)g,
        (__attribute__((address_space(3))) unsigned int*)l, 16, 0, 0);
}

// ---------------- prep_x: per-row i8 quantization of x ----------------
// one block per row; 256 threads x 16 elems (4 float4 chunks, interleaved)
__global__ __launch_bounds__(256) void prep_x(
    const float* __restrict__ X, signed char* __restrict__ Xq,
    float* __restrict__ Scale) {
    const int row = blockIdx.x;
    const int t   = threadIdx.x;
    const float4* xr = reinterpret_cast<const float4*>(X + (size_t)row * K);

    float4 v[4];
    float mx = 0.f;
#pragma unroll
    for (int i = 0; i < 4; ++i) {
        v[i] = xr[t + i * 256];
        mx = fmaxf(mx, fmaxf(fmaxf(fabsf(v[i].x), fabsf(v[i].y)),
                             fmaxf(fabsf(v[i].z), fabsf(v[i].w))));
    }
#pragma unroll
    for (int off = 32; off > 0; off >>= 1)
        mx = fmaxf(mx, __shfl_down(mx, off));
    __shared__ float wmax[4];
    if ((t & 63) == 0) wmax[t >> 6] = mx;
    __syncthreads();
    float rmax = fmaxf(fmaxf(wmax[0], wmax[1]), fmaxf(wmax[2], wmax[3]));
    rmax = fmaxf(rmax, 1e-20f);
    const float inv = 127.f / rmax;
    if (t == 0) Scale[row] = rmax * (1.f / 127.f);

    unsigned int* out = reinterpret_cast<unsigned int*>(Xq + (size_t)row * K);
#pragma unroll
    for (int i = 0; i < 4; ++i) {
        int q0 = (int)rintf(v[i].x * inv);
        int q1 = (int)rintf(v[i].y * inv);
        int q2 = (int)rintf(v[i].z * inv);
        int q3 = (int)rintf(v[i].w * inv);
        unsigned int p = (q0 & 255) | ((q1 & 255) << 8) |
                         ((q2 & 255) << 16) | ((unsigned)(q3 & 255) << 24);
        out[t + i * 256] = p;
    }
}

// ---------------- prep_w: W -> sign i8 ----------------
// one thread = 8 elems (2 float4 loads, one 8B store)
__global__ __launch_bounds__(256) void prep_w(
    const float* __restrict__ W, signed char* __restrict__ Wq) {
    size_t i = (size_t)blockIdx.x * 256 + threadIdx.x;  // chunk of 8 elems
    const float4* s = reinterpret_cast<const float4*>(W) + i * 2;
    float4 a = s[0], b = s[1];
    auto sg = [](float f) -> unsigned int { return (f >= 0.f) ? 1u : 0xFFu; };
    uint2 o;
    o.x = sg(a.x) | (sg(a.y) << 8) | (sg(a.z) << 16) | (sg(a.w) << 24);
    o.y = sg(b.x) | (sg(b.y) << 8) | (sg(b.z) << 16) | (sg(b.w) << 24);
    reinterpret_cast<uint2*>(Wq)[i] = o;
}

// ---------------- GEMM i8 (m97 structure, K-step 64) ----------------
__global__ __launch_bounds__(256) void gemm_i8(
    const signed char* __restrict__ Aq, const signed char* __restrict__ Bq,
    const float* __restrict__ Scale, const float* __restrict__ Bias,
    float* __restrict__ OUT) {
    __shared__ signed char As[MT * KT];  // 8 KB
    __shared__ signed char Bs[NT * KT];  // 8 KB

    const int tid  = threadIdx.x;
    const int lane = tid & 63;
    const int wave = tid >> 6;   // 0..3
    const int wm   = wave >> 1;
    const int wn   = wave & 1;

    const int m0 = blockIdx.y * MT;
    const int n0 = blockIdx.x * NT;

    const int rl  = lane & 15;
    const int kq  = (lane >> 4) * 16;  // byte offset of this lane's k-block (16 i8)

    // staging: wave w covers rows [w*32, w*32+32); lane L -> row +L/4, byte col (L&3)*16
    const int srow = wave * 32 + (lane >> 2);
    const int scol = (lane & 3) * 16;
    const signed char* gA = Aq + (size_t)(m0 + srow) * K + scol;
    const signed char* gB = Bq + (size_t)(n0 + srow) * K + scol;
    signed char* lA0 = &As[(wave * 32) * KT];
    signed char* lA1 = &As[(wave * 32 + 16) * KT];
    signed char* lB0 = &Bs[(wave * 32) * KT];
    signed char* lB1 = &Bs[(wave * 32 + 16) * KT];

    i32x4 acc[4][4];
#pragma unroll
    for (int mi = 0; mi < 4; ++mi)
#pragma unroll
        for (int ni = 0; ni < 4; ++ni)
            acc[mi][ni] = (i32x4){0, 0, 0, 0};

    for (int k0 = 0; k0 < K; k0 += KT) {
        load_lds16(gA + k0, lA0);
        load_lds16(gA + k0 + 16 * K, lA1);
        load_lds16(gB + k0, lB0);
        load_lds16(gB + k0 + 16 * K, lB1);
        __syncthreads();

        i32x4 a[4], b[4];
#pragma unroll
        for (int mi = 0; mi < 4; ++mi)
            a[mi] = *reinterpret_cast<const i32x4*>(&As[(wm * 64 + mi * 16 + rl) * KT + kq]);
#pragma unroll
        for (int ni = 0; ni < 4; ++ni)
            b[ni] = *reinterpret_cast<const i32x4*>(&Bs[(wn * 64 + ni * 16 + rl) * KT + kq]);
#pragma unroll
        for (int mi = 0; mi < 4; ++mi)
#pragma unroll
            for (int ni = 0; ni < 4; ++ni)
                acc[mi][ni] = __builtin_amdgcn_mfma_i32_16x16x64_i8(
                    a[mi], b[ni], acc[mi][ni], 0, 0, 0);
        __syncthreads();
    }

    // epilogue: C/D layout col=lane&15, row=(lane>>4)*4+reg (dtype-independent)
#pragma unroll
    for (int ni = 0; ni < 4; ++ni) {
        int gcol = n0 + wn * 64 + ni * 16 + rl;
        float sb = (Bias[gcol] >= 0.f) ? 1.f : -1.f;
#pragma unroll
        for (int mi = 0; mi < 4; ++mi) {
            int growb = m0 + wm * 64 + mi * 16 + (lane >> 4) * 4;
            float4 sc = *reinterpret_cast<const float4*>(&Scale[growb]);
            OUT[(size_t)(growb + 0) * N + gcol] = (float)acc[mi][ni][0] * sc.x + sb;
            OUT[(size_t)(growb + 1) * N + gcol] = (float)acc[mi][ni][1] * sc.y + sb;
            OUT[(size_t)(growb + 2) * N + gcol] = (float)acc[mi][ni][2] * sc.z + sb;
            OUT[(size_t)(growb + 3) * N + gcol] = (float)acc[mi][ni][3] * sc.w + sb;
        }
    }
}

// ---------------- fallback (R1 kernel): used only if ws_size is too small ----
constexpr int LDSS = 40;
constexpr int KTB  = 32;
__device__ __forceinline__ unsigned short f2b(float f) {
    unsigned int u = __builtin_bit_cast(unsigned int, f);
    u += 0x7FFFu + ((u >> 16) & 1u);
    return (unsigned short)(u >> 16);
}
__global__ __launch_bounds__(256) void binlin_fallback(
    const float* __restrict__ X, const float* __restrict__ W,
    const float* __restrict__ B, float* __restrict__ OUT) {
    __shared__ unsigned short As[MT][LDSS];
    __shared__ unsigned short Bs[NT][LDSS];
    const int tid  = threadIdx.x;
    const int lane = tid & 63;
    const int wave = tid >> 6;
    const int wm   = wave >> 1;
    const int wn   = wave & 1;
    const int m0 = blockIdx.y * MT;
    const int n0 = blockIdx.x * NT;
    const int rl = lane & 15;
    const int kq = (lane >> 4) * 8;
    f32x4 acc[4][4];
#pragma unroll
    for (int mi = 0; mi < 4; ++mi)
#pragma unroll
        for (int ni = 0; ni < 4; ++ni)
            acc[mi][ni] = (f32x4){0.f, 0.f, 0.f, 0.f};
    for (int k0 = 0; k0 < K; k0 += KTB) {
#pragma unroll
        for (int it = 0; it < 4; ++it) {
            int g = tid + it * 256, row = g >> 3, c4 = (g & 7) << 2;
            float4 v = *reinterpret_cast<const float4*>(&X[(size_t)(m0 + row) * K + k0 + c4]);
            ushort4 h;
            h.x = f2b(v.x); h.y = f2b(v.y); h.z = f2b(v.z); h.w = f2b(v.w);
            *reinterpret_cast<ushort4*>(&As[row][c4]) = h;
        }
#pragma unroll
        for (int it = 0; it < 4; ++it) {
            int g = tid + it * 256, row = g >> 3, c4 = (g & 7) << 2;
            float4 v = *reinterpret_cast<const float4*>(&W[(size_t)(n0 + row) * K + k0 + c4]);
            ushort4 h;
            h.x = (v.x >= 0.f) ? 0x3F80u : 0xBF80u;
            h.y = (v.y >= 0.f) ? 0x3F80u : 0xBF80u;
            h.z = (v.z >= 0.f) ? 0x3F80u : 0xBF80u;
            h.w = (v.w >= 0.f) ? 0x3F80u : 0xBF80u;
            *reinterpret_cast<ushort4*>(&Bs[row][c4]) = h;
        }
        __syncthreads();
        short8 a[4], b[4];
#pragma unroll
        for (int mi = 0; mi < 4; ++mi)
            a[mi] = *reinterpret_cast<const short8*>(&As[wm * 64 + mi * 16 + rl][kq]);
#pragma unroll
        for (int ni = 0; ni < 4; ++ni)
            b[ni] = *reinterpret_cast<const short8*>(&Bs[wn * 64 + ni * 16 + rl][kq]);
#pragma unroll
        for (int mi = 0; mi < 4; ++mi)
#pragma unroll
            for (int ni = 0; ni < 4; ++ni)
                acc[mi][ni] = __builtin_amdgcn_mfma_f32_16x16x32_bf16(
                    a[mi], b[ni], acc[mi][ni], 0, 0, 0);
        __syncthreads();
    }
#pragma unroll
    for (int ni = 0; ni < 4; ++ni) {
        int gcol = n0 + wn * 64 + ni * 16 + rl;
        float sb = (B[gcol] >= 0.f) ? 1.f : -1.f;
#pragma unroll
        for (int mi = 0; mi < 4; ++mi) {
            int growb = m0 + wm * 64 + mi * 16 + (lane >> 4) * 4;
#pragma unroll
            for (int r = 0; r < 4; ++r)
                OUT[(size_t)(growb + r) * N + gcol] = acc[mi][ni][r] + sb;
        }
    }
}

extern "C" void kernel_launch(void* const* d_in, const int* in_sizes, int n_in,
                              void* d_out, int out_size, void* d_ws, size_t ws_size,
                              hipStream_t stream) {
    const float* x  = (const float*)d_in[0];
    const float* w  = (const float*)d_in[1];
    const float* b  = (const float*)d_in[2];
    float* out      = (float*)d_out;

    // ws layout: Xq [M*K i8] | Wq [N*K i8] | Scale [M f32]
    const size_t need = (size_t)M * K + (size_t)N * K + (size_t)M * sizeof(float);
    if (ws_size >= need) {
        signed char* Xq = (signed char*)d_ws;
        signed char* Wq = Xq + (size_t)M * K;
        float* Scale    = (float*)(Wq + (size_t)N * K);

        prep_x<<<dim3(M), dim3(256), 0, stream>>>(x, Xq, Scale);
        prep_w<<<dim3((unsigned)((size_t)N * K / 8 / 256)), dim3(256), 0, stream>>>(w, Wq);
        dim3 grid(N / NT, M / MT);  // (32, 64)
        gemm_i8<<<grid, dim3(256), 0, stream>>>(Xq, Wq, Scale, b, out);
    } else {
        dim3 grid(N / NT, M / MT);
        binlin_fallback<<<grid, dim3(256), 0, stream>>>(x, w, b, out);
    }
}